// Round 3
// baseline (983.299 us; speedup 1.0000x reference)
//
#include <hip/hip_runtime.h>
#include <hip/hip_bf16.h>

// ---------- types ----------
typedef __attribute__((ext_vector_type(8))) short short8;
typedef __attribute__((ext_vector_type(4))) float f32x4;
typedef __attribute__((ext_vector_type(4))) int int4v;

#define EMB 128
#define OUT 256
#define NRAD 6
#define NDENSE 3
#define CPAD 16   // counters padded to one per 64B cache line (atomic contention fix)

static __device__ __forceinline__ unsigned short f32_to_bf16(float f) {
    union { float f; unsigned u; } v; v.f = f;
    unsigned r = v.u + 0x7fffu + ((v.u >> 16) & 1u);   // round-nearest-even
    return (unsigned short)(r >> 16);
}
static __device__ __forceinline__ float bf16_to_f32(unsigned short h) {
    union { unsigned u; float f; } v; v.u = ((unsigned)h) << 16;
    return v.f;
}

// ---------- zero (vectorized, replaces hipMemsetAsync) ----------
__global__ void zero_kernel(int4v* __restrict__ p, int n4) {
    int stride = gridDim.x * blockDim.x;
    for (int i = blockIdx.x * blockDim.x + threadIdx.x; i < n4; i += stride)
        p[i] = (int4v){0, 0, 0, 0};
}

// ---------- CSR build (padded counters: 1 per 64B line) ----------
__global__ void hist_kernel(const int* __restrict__ src, int* __restrict__ counts, int E) {
    int stride = gridDim.x * blockDim.x;
    for (int e = blockIdx.x * blockDim.x + threadIdx.x; e < E; e += stride)
        atomicAdd(&counts[(size_t)src[e] * CPAD], 1);
}

__global__ __launch_bounds__(1024) void scan_kernel(const int* __restrict__ counts,
                                                    int* __restrict__ offsets, int n) {
    __shared__ int sums[1024];
    int t = threadIdx.x;
    int chunk = (n + 1023) >> 10;
    int lo = t * chunk;
    int hi = lo + chunk; if (hi > n) hi = n;
    int s = 0;
    for (int i = lo; i < hi; ++i) s += counts[(size_t)i * CPAD];
    sums[t] = s;
    __syncthreads();
    for (int d = 1; d < 1024; d <<= 1) {
        int v = (t >= d) ? sums[t - d] : 0;
        __syncthreads();
        sums[t] += v;
        __syncthreads();
    }
    int base = (t == 0) ? 0 : sums[t - 1];
    for (int i = lo; i < hi; ++i) { offsets[i] = base; base += counts[(size_t)i * CPAD]; }
    if (t == 1023) offsets[n] = base;   // total == E
}

__global__ void scatter_kernel(const int* __restrict__ src, const int* __restrict__ offsets,
                               int* __restrict__ counts /*consumed to 0*/,
                               int* __restrict__ perm, int E) {
    int stride = gridDim.x * blockDim.x;
    for (int e = blockIdx.x * blockDim.x + threadIdx.x; e < E; e += stride) {
        int s = src[e];
        int idx = atomicSub(&counts[(size_t)s * CPAD], 1) - 1;   // unique slot within node
        perm[offsets[s] + idx] = e;
    }
}

// ---------- weight prep (f32 -> bf16) ----------
__global__ void prep_w_kernel(const float* __restrict__ Wup, const float* __restrict__ Wd,
                              unsigned short* __restrict__ out) {
    const int n1 = OUT * EMB;
    const int n2 = NDENSE * OUT * OUT;
    int stride = gridDim.x * blockDim.x;
    for (int i = blockIdx.x * blockDim.x + threadIdx.x; i < n1 + n2; i += stride)
        out[i] = f32_to_bf16(i < n1 ? Wup[i] : Wd[i - n1]);
}

// ---------- fused edge transform + per-node gather-sum ----------
// persistent wave-per-node: lane l owns columns 2l, 2l+1.
// rbf row (24B = 3x float2) loaded with wave-uniform address (1 line/transaction);
// software-pipelined 1-deep prefetch of next edge id + rbf row. No DS ops.
__global__ __launch_bounds__(256) void edge_accum_kernel(
        const float* __restrict__ m, const float* __restrict__ rbf,
        const int* __restrict__ perm, const int* __restrict__ offsets,
        const float* __restrict__ W_rbf, unsigned* __restrict__ t_pack, int N) {
    const int lane = threadIdx.x & 63;
    const int gw = blockIdx.x * (blockDim.x >> 6) + (threadIdx.x >> 6);
    const int nwaves = gridDim.x * (blockDim.x >> 6);

    // per-lane W_rbf rows for cols 2*lane, 2*lane+1 (12 floats, loaded once)
    const float* wr = W_rbf + lane * 2 * NRAD;
    const float wa0 = wr[0], wa1 = wr[1], wa2 = wr[2], wa3 = wr[3], wa4 = wr[4], wa5 = wr[5];
    const float wb0 = wr[6], wb1 = wr[7], wb2 = wr[8], wb3 = wr[9], wb4 = wr[10], wb5 = wr[11];

    for (int node = gw; node < N; node += nwaves) {
        int beg = offsets[node], end = offsets[node + 1];
        float ax = 0.f, ay = 0.f;
        int e0 = 0; float2 q0, q1, q2;
        if (beg < end) {
            e0 = perm[beg];
            const float2* rp = (const float2*)(rbf + (size_t)e0 * NRAD);
            q0 = rp[0]; q1 = rp[1]; q2 = rp[2];
        }
#pragma unroll 2
        for (int i = beg; i < end; ++i) {
            // issue m-load for current edge first
            const float2 mv = *(const float2*)(m + (size_t)e0 * EMB + 2 * lane);
            // prefetch next edge id + rbf row
            int e1 = 0; float2 n0 = q0, n1 = q1, n2 = q2;
            if (i + 1 < end) {
                e1 = perm[i + 1];
                const float2* rp = (const float2*)(rbf + (size_t)e1 * NRAD);
                n0 = rp[0]; n1 = rp[1]; n2 = rp[2];
            }
            float pa = wa0*q0.x + wa1*q0.y + wa2*q1.x + wa3*q1.y + wa4*q2.x + wa5*q2.y;
            float pb = wb0*q0.x + wb1*q0.y + wb2*q1.x + wb3*q1.y + wb4*q2.x + wb5*q2.y;
            ax = fmaf(mv.x, pa, ax);
            ay = fmaf(mv.y, pb, ay);
            e0 = e1; q0 = n0; q1 = n1; q2 = n2;
        }
        unsigned short hx = f32_to_bf16(ax), hy = f32_to_bf16(ay);
        t_pack[(size_t)node * 64 + lane] = (unsigned)hx | ((unsigned)hy << 16);
    }
}

// ---------- bf16 MFMA GEMM: C[M,256] = act(A[M,K] @ Bw^T + bias) ----------
template<int K, int ACT>
__global__ __launch_bounds__(256) void gemm_kernel(
        const unsigned short* __restrict__ A, const unsigned short* __restrict__ Bw,
        const float* __restrict__ bias, unsigned short* __restrict__ C, int M) {
    const int w    = threadIdx.x >> 6;
    const int lane = threadIdx.x & 63;
    const int r     = lane & 15;
    const int khalf = lane >> 4;          // 0..3
    const int row0  = blockIdx.x * 64 + w * 16;

    f32x4 acc[16];
#pragma unroll
    for (int i = 0; i < 16; ++i) acc[i] = (f32x4){0.f, 0.f, 0.f, 0.f};

    const int arow = row0 + r;
    const bool rowok = (arow < M);
    const unsigned short* Arow = A + (size_t)arow * K;

    for (int ks = 0; ks < K; ks += 32) {
        int ka = ks + khalf * 8;
        short8 afrag;
        if (rowok) afrag = *(const short8*)(Arow + ka);
        else       afrag = (short8){0,0,0,0,0,0,0,0};
#pragma unroll
        for (int ct = 0; ct < 16; ++ct) {
            int col = ct * 16 + r;
            short8 bfrag = *(const short8*)(Bw + (size_t)col * K + ka);
            acc[ct] = __builtin_amdgcn_mfma_f32_16x16x32_bf16(afrag, bfrag, acc[ct], 0, 0, 0);
        }
    }

    // epilogue: D layout col=lane&15, row=(lane>>4)*4+reg  [verified m89]
    const int orow_base = row0 + khalf * 4;
#pragma unroll
    for (int ct = 0; ct < 16; ++ct) {
        int col = ct * 16 + r;
        float b = bias ? bias[col] : 0.f;
#pragma unroll
        for (int reg = 0; reg < 4; ++reg) {
            int orow = orow_base + reg;
            if (orow < M) {
                float x = acc[ct][reg] + b;
                if (ACT) x = x / (1.f + __expf(-x));   // silu
                C[(size_t)orow * OUT + col] = f32_to_bf16(x);
            }
        }
    }
}

// ---------- per-graph sum: block per graph, binary search, no atomics ----------
__global__ __launch_bounds__(256) void graph_reduce_kernel(
        const unsigned short* __restrict__ h, const int* __restrict__ gids,
        float* __restrict__ out, int M, int G) {
    int g = blockIdx.x;
    int c = threadIdx.x;
    // lower_bound for g and g+1 over sorted gids[0..M)
    int lo = 0, hi = M;
    while (lo < hi) { int mid = (lo + hi) >> 1; if (gids[mid] < g) lo = mid + 1; else hi = mid; }
    int lo2 = lo, hi2 = M;
    while (lo2 < hi2) { int mid = (lo2 + hi2) >> 1; if (gids[mid] < g + 1) lo2 = mid + 1; else hi2 = mid; }
    // 4 independent partial sums to keep loads in flight
    float a0 = 0.f, a1 = 0.f, a2 = 0.f, a3 = 0.f;
    int n = lo;
    for (; n + 3 < lo2; n += 4) {
        a0 += bf16_to_f32(h[(size_t)(n + 0) * OUT + c]);
        a1 += bf16_to_f32(h[(size_t)(n + 1) * OUT + c]);
        a2 += bf16_to_f32(h[(size_t)(n + 2) * OUT + c]);
        a3 += bf16_to_f32(h[(size_t)(n + 3) * OUT + c]);
    }
    for (; n < lo2; ++n) a0 += bf16_to_f32(h[(size_t)n * OUT + c]);
    out[(size_t)g * OUT + c] = (a0 + a1) + (a2 + a3);
}

// ---------- host ----------
extern "C" void kernel_launch(void* const* d_in, const int* in_sizes, int n_in,
                              void* d_out, int out_size, void* d_ws, size_t ws_size,
                              hipStream_t stream) {
    const float* m         = (const float*)d_in[0];
    const float* rbf       = (const float*)d_in[1];
    const int*   src       = (const int*)d_in[2];
    const int*   gids      = (const int*)d_in[3];
    const float* W_rbf     = (const float*)d_in[4];
    const float* W_up      = (const float*)d_in[5];
    const float* W_dense   = (const float*)d_in[6];
    const float* b_dense   = (const float*)d_in[7];
    float* out = (float*)d_out;

    const int E = in_sizes[2];
    const int N = in_sizes[3];
    const int G = out_size / OUT;

    // workspace layout
    size_t off = 0;
    auto alloc = [&](size_t bytes) -> void* {
        void* p = (char*)d_ws + off;
        off += (bytes + 255) & ~(size_t)255;
        return p;
    };
    int* counts  = (int*)alloc((size_t)N * CPAD * 4);   // padded: 1 counter / 64B line
    int* offsets = (int*)alloc(((size_t)N + 1) * 4);
    int* perm    = (int*)alloc((size_t)E * 4);
    unsigned short* t_bf = (unsigned short*)alloc((size_t)N * EMB * 2);
    unsigned short* h0   = (unsigned short*)alloc((size_t)N * OUT * 2);
    unsigned short* h1   = (unsigned short*)alloc((size_t)N * OUT * 2);
    unsigned short* Wbf  = (unsigned short*)alloc((size_t)(OUT * EMB + NDENSE * OUT * OUT) * 2);
    unsigned short* Wup_bf = Wbf;
    unsigned short* Wd_bf  = Wbf + OUT * EMB;

    // CSR build (padded counters kill L2 line-contention on atomics)
    zero_kernel<<<2048, 256, 0, stream>>>((int4v*)counts, N * CPAD / 4);
    hist_kernel<<<1024, 256, 0, stream>>>(src, counts, E);
    scan_kernel<<<1, 1024, 0, stream>>>(counts, offsets, N);
    scatter_kernel<<<1024, 256, 0, stream>>>(src, offsets, counts, perm, E);

    // weights -> bf16
    prep_w_kernel<<<256, 256, 0, stream>>>(W_up, W_dense, Wbf);

    // edge transform + node gather (persistent, 8192 waves = 32/CU)
    edge_accum_kernel<<<2048, 256, 0, stream>>>(m, rbf, perm, offsets, W_rbf,
                                                (unsigned*)t_bf, N);

    // up-projection (no bias, no act), then 3 dense+silu layers
    int gblocks = (N + 63) / 64;
    gemm_kernel<EMB, 0><<<gblocks, 256, 0, stream>>>(t_bf, Wup_bf, nullptr, h0, N);
    gemm_kernel<OUT, 1><<<gblocks, 256, 0, stream>>>(h0, Wd_bf + 0 * OUT * OUT, b_dense + 0 * OUT, h1, N);
    gemm_kernel<OUT, 1><<<gblocks, 256, 0, stream>>>(h1, Wd_bf + 1 * OUT * OUT, b_dense + 1 * OUT, h0, N);
    gemm_kernel<OUT, 1><<<gblocks, 256, 0, stream>>>(h0, Wd_bf + 2 * OUT * OUT, b_dense + 2 * OUT, h1, N);

    // per-graph readout (deterministic, atomic-free)
    graph_reduce_kernel<<<G, 256, 0, stream>>>(h1, gids, out, N, G);
}

// Round 4
// 885.265 us; speedup vs baseline: 1.1107x; 1.1107x over previous
//
#include <hip/hip_runtime.h>
#include <hip/hip_bf16.h>

// ---------- types ----------
typedef __attribute__((ext_vector_type(8))) short short8;
typedef __attribute__((ext_vector_type(4))) float f32x4;
typedef __attribute__((ext_vector_type(4))) int int4v;

#define EMB 128
#define OUT 256
#define NRAD 6
#define NDENSE 3
#define SCAN_NB 256   // blocks in hierarchical scan

static __device__ __forceinline__ unsigned short f32_to_bf16(float f) {
    union { float f; unsigned u; } v; v.f = f;
    unsigned r = v.u + 0x7fffu + ((v.u >> 16) & 1u);   // round-nearest-even
    return (unsigned short)(r >> 16);
}
static __device__ __forceinline__ float bf16_to_f32(unsigned short h) {
    union { unsigned u; float f; } v; v.u = ((unsigned)h) << 16;
    return v.f;
}
static __device__ __forceinline__ float silu(float x) {
    return x / (1.f + __expf(-x));
}

// ---------- zero (vectorized) ----------
__global__ void zero_kernel(int4v* __restrict__ p, int n4) {
    int stride = gridDim.x * blockDim.x;
    for (int i = blockIdx.x * blockDim.x + threadIdx.x; i < n4; i += stride)
        p[i] = (int4v){0, 0, 0, 0};
}

// ---------- CSR build ----------
__global__ void hist_kernel(const int* __restrict__ src, int* __restrict__ counts, int E) {
    int stride = gridDim.x * blockDim.x;
    for (int e = blockIdx.x * blockDim.x + threadIdx.x; e < E; e += stride)
        atomicAdd(&counts[src[e]], 1);
}

// 3-phase hierarchical exclusive scan of counts[N] -> offsets[N+1]
__global__ __launch_bounds__(256) void scanA_kernel(const int* __restrict__ counts,
                                                    int* __restrict__ bsum, int N, int chunk) {
    __shared__ int red[256];
    int b = blockIdx.x, t = threadIdx.x;
    int idx = b * chunk + t;
    int v = (t < chunk && idx < N) ? counts[idx] : 0;
    red[t] = v;
    __syncthreads();
    for (int d = 128; d > 0; d >>= 1) {
        if (t < d) red[t] += red[t + d];
        __syncthreads();
    }
    if (t == 0) bsum[b] = red[0];
}

__global__ __launch_bounds__(256) void scanB_kernel(int* __restrict__ bsum,
                                                    int* __restrict__ bpre,
                                                    int* __restrict__ offsets, int N) {
    __shared__ int s[256];
    int t = threadIdx.x;
    int v = bsum[t];
    s[t] = v;
    __syncthreads();
    for (int d = 1; d < 256; d <<= 1) {
        int x = (t >= d) ? s[t - d] : 0;
        __syncthreads();
        s[t] += x;
        __syncthreads();
    }
    bpre[t] = s[t] - v;             // exclusive
    if (t == 255) offsets[N] = s[t]; // total == E
}

__global__ __launch_bounds__(256) void scanC_kernel(const int* __restrict__ counts,
                                                    const int* __restrict__ bpre,
                                                    int* __restrict__ offsets, int N, int chunk) {
    __shared__ int s[256];
    int b = blockIdx.x, t = threadIdx.x;
    int idx = b * chunk + t;
    int v = (t < chunk && idx < N) ? counts[idx] : 0;
    s[t] = v;
    __syncthreads();
    for (int d = 1; d < 256; d <<= 1) {
        int x = (t >= d) ? s[t - d] : 0;
        __syncthreads();
        s[t] += x;
        __syncthreads();
    }
    if (t < chunk && idx < N) offsets[idx] = bpre[b] + s[t] - v;
}

__global__ void scatter_kernel(const int* __restrict__ src, const int* __restrict__ offsets,
                               int* __restrict__ counts /*consumed to 0*/,
                               int* __restrict__ perm, int E) {
    int stride = gridDim.x * blockDim.x;
    for (int e = blockIdx.x * blockDim.x + threadIdx.x; e < E; e += stride) {
        int s = src[e];
        int idx = atomicSub(&counts[s], 1) - 1;   // unique slot within node
        perm[offsets[s] + idx] = e;
    }
}

// ---------- weight prep (f32 -> bf16) ----------
__global__ void prep_w_kernel(const float* __restrict__ Wup, const float* __restrict__ Wd,
                              unsigned short* __restrict__ out) {
    const int n1 = OUT * EMB;
    const int n2 = NDENSE * OUT * OUT;
    int stride = gridDim.x * blockDim.x;
    for (int i = blockIdx.x * blockDim.x + threadIdx.x; i < n1 + n2; i += stride)
        out[i] = f32_to_bf16(i < n1 ? Wup[i] : Wd[i - n1]);
}

// ---------- fused edge transform + per-node gather-sum (4-edge ILP) ----------
// persistent wave-per-node: lane l owns columns 2l, 2l+1.
// Per chunk: 4 perm ids -> 4 independent rbf rows + 4 independent 512B m rows
// all in flight before any use -> 4x memory-level parallelism per wave.
__global__ __launch_bounds__(256) void edge_accum_kernel(
        const float* __restrict__ m, const float* __restrict__ rbf,
        const int* __restrict__ perm, const int* __restrict__ offsets,
        const float* __restrict__ W_rbf, unsigned* __restrict__ t_pack, int N) {
    const int lane = threadIdx.x & 63;
    const int gw = blockIdx.x * (blockDim.x >> 6) + (threadIdx.x >> 6);
    const int nwaves = gridDim.x * (blockDim.x >> 6);

    const float* wr = W_rbf + lane * 2 * NRAD;
    const float wa0 = wr[0], wa1 = wr[1], wa2 = wr[2], wa3 = wr[3], wa4 = wr[4], wa5 = wr[5];
    const float wb0 = wr[6], wb1 = wr[7], wb2 = wr[8], wb3 = wr[9], wb4 = wr[10], wb5 = wr[11];

    for (int node = gw; node < N; node += nwaves) {
        int beg = offsets[node], end = offsets[node + 1];
        float ax = 0.f, ay = 0.f;
        for (int i = beg; i < end; i += 4) {
            int rem = end - i;
            int i1 = (rem > 1) ? i + 1 : i;
            int i2 = (rem > 2) ? i + 2 : i;
            int i3 = (rem > 3) ? i + 3 : i;
            int e0 = perm[i], e1 = perm[i1], e2 = perm[i2], e3 = perm[i3];
            // 4 independent rbf rows (wave-uniform addresses)
            const float2* rp0 = (const float2*)(rbf + (size_t)e0 * NRAD);
            const float2* rp1 = (const float2*)(rbf + (size_t)e1 * NRAD);
            const float2* rp2 = (const float2*)(rbf + (size_t)e2 * NRAD);
            const float2* rp3 = (const float2*)(rbf + (size_t)e3 * NRAD);
            float2 q00 = rp0[0], q01 = rp0[1], q02 = rp0[2];
            float2 q10 = rp1[0], q11 = rp1[1], q12 = rp1[2];
            float2 q20 = rp2[0], q21 = rp2[1], q22 = rp2[2];
            float2 q30 = rp3[0], q31 = rp3[1], q32 = rp3[2];
            // 4 independent m rows (512B coalesced each)
            const float2 m0 = *(const float2*)(m + (size_t)e0 * EMB + 2 * lane);
            const float2 m1 = *(const float2*)(m + (size_t)e1 * EMB + 2 * lane);
            const float2 m2 = *(const float2*)(m + (size_t)e2 * EMB + 2 * lane);
            const float2 m3 = *(const float2*)(m + (size_t)e3 * EMB + 2 * lane);
            float g1 = (rem > 1) ? 1.f : 0.f;
            float g2 = (rem > 2) ? 1.f : 0.f;
            float g3 = (rem > 3) ? 1.f : 0.f;
            float pa0 = wa0*q00.x + wa1*q00.y + wa2*q01.x + wa3*q01.y + wa4*q02.x + wa5*q02.y;
            float pb0 = wb0*q00.x + wb1*q00.y + wb2*q01.x + wb3*q01.y + wb4*q02.x + wb5*q02.y;
            float pa1 = (wa0*q10.x + wa1*q10.y + wa2*q11.x + wa3*q11.y + wa4*q12.x + wa5*q12.y) * g1;
            float pb1 = (wb0*q10.x + wb1*q10.y + wb2*q11.x + wb3*q11.y + wb4*q12.x + wb5*q12.y) * g1;
            float pa2 = (wa0*q20.x + wa1*q20.y + wa2*q21.x + wa3*q21.y + wa4*q22.x + wa5*q22.y) * g2;
            float pb2 = (wb0*q20.x + wb1*q20.y + wb2*q21.x + wb3*q21.y + wb4*q22.x + wb5*q22.y) * g2;
            float pa3 = (wa0*q30.x + wa1*q30.y + wa2*q31.x + wa3*q31.y + wa4*q32.x + wa5*q32.y) * g3;
            float pb3 = (wb0*q30.x + wb1*q30.y + wb2*q31.x + wb3*q31.y + wb4*q32.x + wb5*q32.y) * g3;
            ax = fmaf(m0.x, pa0, ax); ay = fmaf(m0.y, pb0, ay);
            ax = fmaf(m1.x, pa1, ax); ay = fmaf(m1.y, pb1, ay);
            ax = fmaf(m2.x, pa2, ax); ay = fmaf(m2.y, pb2, ay);
            ax = fmaf(m3.x, pa3, ax); ay = fmaf(m3.y, pb3, ay);
        }
        unsigned short hx = f32_to_bf16(ax), hy = f32_to_bf16(ay);
        t_pack[(size_t)node * 64 + lane] = (unsigned)hx | ((unsigned)hy << 16);
    }
}

// ---------- fused MLP: up-proj + 3x (dense + silu), one kernel ----------
// Block = 256 threads (4 waves); block tile = 64 rows; wave w owns rows
// [blk*64+w*16, +16) through ALL layers (rows are independent across layers).
// Inter-layer staging in wave-local LDS [16][256] bf16 with XOR swizzle
// byte ^= ((row&7)<<4) so stride-512B A-fragment ds_read_b128 is conflict-free.
__global__ __launch_bounds__(256) void fused_mlp_kernel(
        const unsigned short* __restrict__ A0,    // [M,128] bf16
        const unsigned short* __restrict__ Wup,   // [256,128] bf16
        const unsigned short* __restrict__ Wd,    // [3,256,256] bf16
        const float* __restrict__ bd,             // [3,256]
        unsigned short* __restrict__ Hout, int M) {
    __shared__ unsigned short smem[4][16 * 256];
    const int w    = threadIdx.x >> 6;
    const int lane = threadIdx.x & 63;
    const int r    = lane & 15;
    const int g    = lane >> 4;          // khalf / row-group
    const int row0 = blockIdx.x * 64 + w * 16;
    char* swc = (char*)&smem[w][0];

    f32x4 acc[16];
#pragma unroll
    for (int i = 0; i < 16; ++i) acc[i] = (f32x4){0.f, 0.f, 0.f, 0.f};

    // ---- layer 0: up-projection, K=128, A from global ----
    const int arow = row0 + r;
    const bool rowok = (arow < M);
    const unsigned short* Arow = A0 + (size_t)arow * EMB;
#pragma unroll
    for (int ks = 0; ks < EMB; ks += 32) {
        int ka = ks + g * 8;
        short8 afrag;
        if (rowok) afrag = *(const short8*)(Arow + ka);
        else       afrag = (short8){0,0,0,0,0,0,0,0};
#pragma unroll
        for (int ct = 0; ct < 16; ++ct) {
            int col = ct * 16 + r;
            short8 bfrag = *(const short8*)(Wup + (size_t)col * EMB + ka);
            acc[ct] = __builtin_amdgcn_mfma_f32_16x16x32_bf16(afrag, bfrag, acc[ct], 0, 0, 0);
        }
    }

    // stash layer-0 output (no bias/act) into LDS
#pragma unroll
    for (int ct = 0; ct < 16; ++ct) {
        int col = ct * 16 + r;
#pragma unroll
        for (int reg = 0; reg < 4; ++reg) {
            int rw = 4 * g + reg;
            int byte = rw * 512 + col * 2;
            byte ^= (rw & 7) << 4;
            *(unsigned short*)(swc + byte) = f32_to_bf16(acc[ct][reg]);
        }
    }
    __syncthreads();

    // ---- layers 1..3: dense 256x256 + bias + silu ----
    for (int ell = 0; ell < NDENSE; ++ell) {
        const unsigned short* Bl = Wd + (size_t)ell * OUT * OUT;
        const float* bias = bd + ell * OUT;
#pragma unroll
        for (int i = 0; i < 16; ++i) acc[i] = (f32x4){0.f, 0.f, 0.f, 0.f};
#pragma unroll
        for (int ks = 0; ks < 8; ++ks) {
            int byte = r * 512 + ks * 64 + g * 16;
            byte ^= (r & 7) << 4;
            short8 afrag = *(const short8*)(swc + byte);
            int ka = ks * 32 + g * 8;
#pragma unroll
            for (int ct = 0; ct < 16; ++ct) {
                int col = ct * 16 + r;
                short8 bfrag = *(const short8*)(Bl + (size_t)col * OUT + ka);
                acc[ct] = __builtin_amdgcn_mfma_f32_16x16x32_bf16(afrag, bfrag, acc[ct], 0, 0, 0);
            }
        }
        if (ell < NDENSE - 1) {
            __syncthreads();   // everyone done reading before overwrite
#pragma unroll
            for (int ct = 0; ct < 16; ++ct) {
                int col = ct * 16 + r;
                float b = bias[col];
#pragma unroll
                for (int reg = 0; reg < 4; ++reg) {
                    int rw = 4 * g + reg;
                    int byte = rw * 512 + col * 2;
                    byte ^= (rw & 7) << 4;
                    *(unsigned short*)(swc + byte) = f32_to_bf16(silu(acc[ct][reg] + b));
                }
            }
            __syncthreads();
        } else {
            // final layer -> global
            const int orow_base = row0 + g * 4;
#pragma unroll
            for (int ct = 0; ct < 16; ++ct) {
                int col = ct * 16 + r;
                float b = bias[col];
#pragma unroll
                for (int reg = 0; reg < 4; ++reg) {
                    int orow = orow_base + reg;
                    if (orow < M)
                        Hout[(size_t)orow * OUT + col] = f32_to_bf16(silu(acc[ct][reg] + b));
                }
            }
        }
    }
}

// ---------- per-graph sum: 4 deterministic partials + combine ----------
__global__ __launch_bounds__(256) void graph_partial_kernel(
        const unsigned short* __restrict__ h, const int* __restrict__ gids,
        float* __restrict__ partial, int M) {
    int gph = blockIdx.x, s = blockIdx.y;
    int c = threadIdx.x;
    int lo = 0, hi = M;
    while (lo < hi) { int mid = (lo + hi) >> 1; if (gids[mid] < gph) lo = mid + 1; else hi = mid; }
    int lo2 = lo, hi2 = M;
    while (lo2 < hi2) { int mid = (lo2 + hi2) >> 1; if (gids[mid] < gph + 1) lo2 = mid + 1; else hi2 = mid; }
    int len = lo2 - lo;
    int q = (len + 3) >> 2;
    int b0 = lo + s * q;
    int b1 = b0 + q; if (b1 > lo2) b1 = lo2;
    float a0 = 0.f, a1 = 0.f;
    int n = b0;
    for (; n + 1 < b1; n += 2) {
        a0 += bf16_to_f32(h[(size_t)n * OUT + c]);
        a1 += bf16_to_f32(h[(size_t)(n + 1) * OUT + c]);
    }
    for (; n < b1; ++n) a0 += bf16_to_f32(h[(size_t)n * OUT + c]);
    partial[((size_t)gph * 4 + s) * OUT + c] = a0 + a1;
}

__global__ __launch_bounds__(256) void graph_final_kernel(
        const float* __restrict__ partial, float* __restrict__ out) {
    int gph = blockIdx.x, c = threadIdx.x;
    const float* p = partial + (size_t)gph * 4 * OUT + c;
    out[(size_t)gph * OUT + c] = (p[0] + p[OUT]) + (p[2 * OUT] + p[3 * OUT]);
}

// ---------- host ----------
extern "C" void kernel_launch(void* const* d_in, const int* in_sizes, int n_in,
                              void* d_out, int out_size, void* d_ws, size_t ws_size,
                              hipStream_t stream) {
    const float* m         = (const float*)d_in[0];
    const float* rbf       = (const float*)d_in[1];
    const int*   src       = (const int*)d_in[2];
    const int*   gids      = (const int*)d_in[3];
    const float* W_rbf     = (const float*)d_in[4];
    const float* W_up      = (const float*)d_in[5];
    const float* W_dense   = (const float*)d_in[6];
    const float* b_dense   = (const float*)d_in[7];
    float* out = (float*)d_out;

    const int E = in_sizes[2];
    const int N = in_sizes[3];
    const int G = out_size / OUT;

    size_t off = 0;
    auto alloc = [&](size_t bytes) -> void* {
        void* p = (char*)d_ws + off;
        off += (bytes + 255) & ~(size_t)255;
        return p;
    };
    int* counts  = (int*)alloc((size_t)N * 4);
    int* offsets = (int*)alloc(((size_t)N + 1) * 4);
    int* perm    = (int*)alloc((size_t)E * 4);
    int* bsum    = (int*)alloc(SCAN_NB * 4);
    int* bpre    = (int*)alloc(SCAN_NB * 4);
    unsigned short* t_bf = (unsigned short*)alloc((size_t)N * EMB * 2);
    unsigned short* hbuf = (unsigned short*)alloc((size_t)N * OUT * 2);
    float* partial       = (float*)alloc((size_t)G * 4 * OUT * 4);
    unsigned short* Wbf  = (unsigned short*)alloc((size_t)(OUT * EMB + NDENSE * OUT * OUT) * 2);
    unsigned short* Wup_bf = Wbf;
    unsigned short* Wd_bf  = Wbf + OUT * EMB;

    const int chunk = (N + SCAN_NB - 1) / SCAN_NB;   // 196 for N=50000 (fits 256 threads)

    // CSR build
    zero_kernel<<<64, 256, 0, stream>>>((int4v*)counts, N / 4);
    hist_kernel<<<1024, 256, 0, stream>>>(src, counts, E);
    scanA_kernel<<<SCAN_NB, 256, 0, stream>>>(counts, bsum, N, chunk);
    scanB_kernel<<<1, 256, 0, stream>>>(bsum, bpre, offsets, N);
    scanC_kernel<<<SCAN_NB, 256, 0, stream>>>(counts, bpre, offsets, N, chunk);
    scatter_kernel<<<1024, 256, 0, stream>>>(src, offsets, counts, perm, E);

    // weights -> bf16
    prep_w_kernel<<<256, 256, 0, stream>>>(W_up, W_dense, Wbf);

    // edge transform + node gather (persistent, 8192 waves = 32/CU)
    edge_accum_kernel<<<2048, 256, 0, stream>>>(m, rbf, perm, offsets, W_rbf,
                                                (unsigned*)t_bf, N);

    // fused up-proj + 3x dense+silu
    fused_mlp_kernel<<<(N + 63) / 64, 256, 0, stream>>>(t_bf, Wup_bf, Wd_bf, b_dense, hbuf, N);

    // per-graph readout (deterministic)
    graph_partial_kernel<<<dim3(G, 4), 256, 0, stream>>>(hbuf, gids, partial, N);
    graph_final_kernel<<<G, 256, 0, stream>>>(partial, out);
}